// Round 4
// baseline (690.885 us; speedup 1.0000x reference)
//
#include <hip/hip_runtime.h>
#include <math.h>

typedef unsigned short u16;

#define BN 16
#define N 2048
#define D 256
#define PAIRS 8
#define NO 2049
#define NEGMIN  -3.40282347e38f   // f32 lowest (softmax-internal sentinel)
#define MASKVAL -3.0e38f          // stored sentinel: finite in bf16

// ws float region (float offsets within wsf)
#define WS_LS0   0
#define WS_LS1   (1*PAIRS*N)
#define WS_LSN0  (2*PAIRS*N)
#define WS_LSN1  (3*PAIRS*N)
#define WS_RMAX  (4*PAIRS*N)
#define WS_RLSE  (5*PAIRS*N)
#define WS_CMAX  (6*PAIRS*N)
#define WS_CLSE  (7*PAIRS*N)
#define WS_F_COUNT (8*PAIRS*N)    // floats; f32 mdesc follows

__device__ __forceinline__ float b2f(u16 u) {
    return __uint_as_float(((unsigned)u) << 16);
}
__device__ __forceinline__ u16 f2b(float f) {  // RNE f32 -> bf16 (finite inputs only)
    unsigned x = __float_as_uint(f);
    x += 0x7FFFu + ((x >> 16) & 1u);
    return (u16)(x >> 16);
}
__device__ __forceinline__ float logsig(float x) {
    return fminf(x, 0.f) - log1pf(expf(-fabsf(x)));
}

// ---- matchability: m[b][i] = desc[b][i] . match_w + match_b (f32 inputs)
__global__ __launch_bounds__(256) void k_match(const float* __restrict__ desc,
                                               const float* __restrict__ mw,
                                               const float* __restrict__ mb,
                                               float* __restrict__ wsf) {
    int row = blockIdx.x * 4 + (threadIdx.x >> 6);   // 4 waves/block, 1 row each
    int lane = threadIdx.x & 63;
    float4 d = *(const float4*)(desc + (size_t)row * D + lane * 4);
    float4 w = *(const float4*)(mw + lane * 4);
    float s = d.x * w.x + d.y * w.y + d.z * w.z + d.w * w.w;
    #pragma unroll
    for (int off = 32; off > 0; off >>= 1) s += __shfl_down(s, off, 64);
    if (lane == 0) {
        float m = s + mb[0];
        int b = row >> 11;          // row / N
        int i = row & (N - 1);
        int p = b >> 1, sid = b & 1;
        float ls  = logsig(m);
        float lsn = logsig(-m);
        if (sid == 0) { wsf[WS_LS0 + p*N + i] = ls; wsf[WS_LSN0 + p*N + i] = lsn; }
        else          { wsf[WS_LS1 + p*N + i] = ls; wsf[WS_LSN1 + p*N + i] = lsn; }
    }
}

// ---- projection GEMM (f32): mdesc = (desc @ W^T + b) / d^0.25  (d^0.25 = 4)
__global__ __launch_bounds__(256) void k_proj(const float* __restrict__ A,
                                              const float* __restrict__ W,
                                              const float* __restrict__ bias,
                                              float* __restrict__ mdesc) {
    __shared__ float As[16][68];
    __shared__ float Bs[16][68];
    int r0 = blockIdx.x * 64;
    int j0 = blockIdx.y * 64;
    int tid = threadIdx.x;
    int lrow = tid >> 2;
    int lk = (tid & 3) * 4;
    int ty = tid >> 4, tx = tid & 15;
    float acc[4][4] = {};
    for (int k0 = 0; k0 < D; k0 += 16) {
        float4 va = *(const float4*)&A[(size_t)(r0 + lrow) * D + k0 + lk];
        float4 vb = *(const float4*)&W[(size_t)(j0 + lrow) * D + k0 + lk];
        __syncthreads();
        As[lk+0][lrow] = va.x; As[lk+1][lrow] = va.y; As[lk+2][lrow] = va.z; As[lk+3][lrow] = va.w;
        Bs[lk+0][lrow] = vb.x; Bs[lk+1][lrow] = vb.y; Bs[lk+2][lrow] = vb.z; Bs[lk+3][lrow] = vb.w;
        __syncthreads();
        #pragma unroll
        for (int k = 0; k < 16; ++k) {
            float4 a = *(const float4*)&As[k][ty * 4];
            float4 b = *(const float4*)&Bs[k][tx * 4];
            acc[0][0] += a.x*b.x; acc[0][1] += a.x*b.y; acc[0][2] += a.x*b.z; acc[0][3] += a.x*b.w;
            acc[1][0] += a.y*b.x; acc[1][1] += a.y*b.y; acc[1][2] += a.y*b.z; acc[1][3] += a.y*b.w;
            acc[2][0] += a.z*b.x; acc[2][1] += a.z*b.y; acc[2][2] += a.z*b.z; acc[2][3] += a.z*b.w;
            acc[3][0] += a.w*b.x; acc[3][1] += a.w*b.y; acc[3][2] += a.w*b.z; acc[3][3] += a.w*b.w;
        }
    }
    float4 bj = *(const float4*)&bias[j0 + tx * 4];
    #pragma unroll
    for (int u = 0; u < 4; ++u) {
        float4 o;
        o.x = (acc[u][0] + bj.x) * 0.25f;
        o.y = (acc[u][1] + bj.y) * 0.25f;
        o.z = (acc[u][2] + bj.z) * 0.25f;
        o.w = (acc[u][3] + bj.w) * 0.25f;
        *(float4*)&mdesc[(size_t)(r0 + ty * 4 + u) * D + j0 + tx * 4] = o;
    }
}

// ---- similarity (f32 math): S = A0 @ A1^T, masked -> MASKVAL, stored bf16
__global__ __launch_bounds__(256) void k_sim(const float* __restrict__ mdesc,
                                             const int* __restrict__ mask,
                                             u16* __restrict__ out) {
    __shared__ float As[16][68];
    __shared__ float Bs[16][68];
    int p = blockIdx.z;
    const float* A  = mdesc + (size_t)(2*p) * N * D;
    const float* Bm = mdesc + (size_t)(2*p+1) * N * D;
    const int* m0 = mask + (size_t)(2*p) * N;
    const int* m1 = mask + (size_t)(2*p+1) * N;
    u16* outp = out + (size_t)p * NO * NO;
    int r0 = blockIdx.x * 64;
    int j0 = blockIdx.y * 64;
    int tid = threadIdx.x;
    int lrow = tid >> 2;
    int lk = (tid & 3) * 4;
    int ty = tid >> 4, tx = tid & 15;
    float acc[4][4] = {};
    for (int k0 = 0; k0 < D; k0 += 16) {
        float4 va = *(const float4*)&A [(size_t)(r0 + lrow) * D + k0 + lk];
        float4 vb = *(const float4*)&Bm[(size_t)(j0 + lrow) * D + k0 + lk];
        __syncthreads();
        As[lk+0][lrow] = va.x; As[lk+1][lrow] = va.y; As[lk+2][lrow] = va.z; As[lk+3][lrow] = va.w;
        Bs[lk+0][lrow] = vb.x; Bs[lk+1][lrow] = vb.y; Bs[lk+2][lrow] = vb.z; Bs[lk+3][lrow] = vb.w;
        __syncthreads();
        #pragma unroll
        for (int k = 0; k < 16; ++k) {
            float4 a = *(const float4*)&As[k][ty * 4];
            float4 b = *(const float4*)&Bs[k][tx * 4];
            acc[0][0] += a.x*b.x; acc[0][1] += a.x*b.y; acc[0][2] += a.x*b.z; acc[0][3] += a.x*b.w;
            acc[1][0] += a.y*b.x; acc[1][1] += a.y*b.y; acc[1][2] += a.y*b.z; acc[1][3] += a.y*b.w;
            acc[2][0] += a.z*b.x; acc[2][1] += a.z*b.y; acc[2][2] += a.z*b.z; acc[2][3] += a.z*b.w;
            acc[3][0] += a.w*b.x; acc[3][1] += a.w*b.y; acc[3][2] += a.w*b.z; acc[3][3] += a.w*b.w;
        }
    }
    int mu[4], mv[4];
    #pragma unroll
    for (int u = 0; u < 4; ++u) mu[u] = m0[r0 + ty*4 + u];
    #pragma unroll
    for (int v = 0; v < 4; ++v) mv[v] = m1[j0 + tx*4 + v];
    #pragma unroll
    for (int u = 0; u < 4; ++u) {
        size_t base = (size_t)(r0 + ty*4 + u) * NO + j0 + tx*4;
        #pragma unroll
        for (int v = 0; v < 4; ++v) {
            outp[base + v] = f2b((mu[u] && mv[v]) ? acc[u][v] : MASKVAL);
        }
    }
}

// ---- row stats: max + log(sum exp(x-max)) per row (bf16 reads)
__global__ __launch_bounds__(256) void k_rowstats(const u16* __restrict__ out,
                                                  float* __restrict__ wsf) {
    int i = blockIdx.x, p = blockIdx.y;
    const u16* row = out + (size_t)p * NO * NO + (size_t)i * NO;
    __shared__ float buf[N];
    __shared__ float red[256];
    int tid = threadIdx.x;
    float mx = NEGMIN;
    for (int j = tid; j < N; j += 256) { float v = b2f(row[j]); buf[j] = v; mx = fmaxf(mx, v); }
    red[tid] = mx;
    __syncthreads();
    for (int s = 128; s > 0; s >>= 1) {
        if (tid < s) red[tid] = fmaxf(red[tid], red[tid + s]);
        __syncthreads();
    }
    mx = red[0];
    __syncthreads();
    float sum = 0.f;
    for (int j = tid; j < N; j += 256) sum += expf(buf[j] - mx);
    red[tid] = sum;
    __syncthreads();
    for (int s = 128; s > 0; s >>= 1) {
        if (tid < s) red[tid] += red[tid + s];
        __syncthreads();
    }
    if (tid == 0) {
        wsf[WS_RMAX + p * N + i] = mx;
        wsf[WS_RLSE + p * N + i] = logf(red[0]);
    }
}

// ---- col stats: online max/sumexp per column, 64-col tiles (bf16 reads)
__global__ __launch_bounds__(256) void k_colstats(const u16* __restrict__ out,
                                                  float* __restrict__ wsf) {
    int p = blockIdx.y;
    int j0 = blockIdx.x * 64;
    int c = threadIdx.x & 63, q = threadIdx.x >> 6;
    const u16* outp = out + (size_t)p * NO * NO;
    float m = NEGMIN, s = 0.f;
    for (int r = q; r < N; r += 4) {
        float x = b2f(outp[(size_t)r * NO + j0 + c]);
        float nm = fmaxf(m, x);
        s = s * expf(m - nm) + expf(x - nm);
        m = nm;
    }
    __shared__ float sm[4][64], ss[4][64];
    sm[q][c] = m; ss[q][c] = s;
    __syncthreads();
    if (threadIdx.x < 64) {
        int j = threadIdx.x;
        float M = fmaxf(fmaxf(sm[0][j], sm[1][j]), fmaxf(sm[2][j], sm[3][j]));
        float S = ss[0][j] * expf(sm[0][j] - M) + ss[1][j] * expf(sm[1][j] - M)
                + ss[2][j] * expf(sm[2][j] - M) + ss[3][j] * expf(sm[3][j] - M);
        wsf[WS_CMAX + p * N + j0 + j] = M;
        wsf[WS_CLSE + p * N + j0 + j] = logf(S);
    }
}

// ---- final: in-place transform + borders (bf16 in/out, all-finite stores)
__global__ __launch_bounds__(256) void k_final(u16* __restrict__ out,
                                               const float* __restrict__ wsf) {
    int i = blockIdx.x, p = blockIdx.y;
    u16* row = out + (size_t)p * NO * NO + (size_t)i * NO;
    int tid = threadIdx.x;
    if (i < N) {
        float rm  = wsf[WS_RMAX + p * N + i];
        float rl  = wsf[WS_RLSE + p * N + i];
        float l0  = wsf[WS_LS0  + p * N + i];
        float ln0 = wsf[WS_LSN0 + p * N + i];
        for (int j = tid; j <= N; j += 256) {
            if (j < N) {
                float v = b2f(row[j]);
                float a = (v - rm) - rl;
                float b = (v - wsf[WS_CMAX + p * N + j]) - wsf[WS_CLSE + p * N + j];
                // masked: a,b ~ -3e38 each; a+b -> -inf transiently; fmaxf scrubs it
                float sab = fmaxf(a + b, MASKVAL);
                row[j] = f2b(fmaxf(sab + (l0 + wsf[WS_LS1 + p * N + j]), MASKVAL));
            } else {
                row[N] = f2b(ln0);
            }
        }
    } else {
        for (int j = tid; j <= N; j += 256) {
            row[j] = (j < N) ? f2b(wsf[WS_LSN1 + p * N + j]) : (u16)0;
        }
    }
}

extern "C" void kernel_launch(void* const* d_in, const int* in_sizes, int n_in,
                              void* d_out, int out_size, void* d_ws, size_t ws_size,
                              hipStream_t stream) {
    const float* desc    = (const float*)d_in[0];
    const int*   mask    = (const int*)d_in[1];
    const float* proj_w  = (const float*)d_in[2];
    const float* proj_b  = (const float*)d_in[3];
    const float* match_w = (const float*)d_in[4];
    const float* match_b = (const float*)d_in[5];
    u16*   out = (u16*)d_out;        // output buffer is bf16
    float* wsf = (float*)d_ws;
    float* mdesc = wsf + WS_F_COUNT; // f32 mdesc, 64 MB

    k_match   <<<dim3(8192),        256, 0, stream>>>(desc, match_w, match_b, wsf);
    k_proj    <<<dim3(512, 4),      256, 0, stream>>>(desc, proj_w, proj_b, mdesc);
    k_sim     <<<dim3(32, 32, 8),   256, 0, stream>>>(mdesc, mask, out);
    k_rowstats<<<dim3(2048, 8),     256, 0, stream>>>(out, wsf);
    k_colstats<<<dim3(32, 8),       256, 0, stream>>>(out, wsf);
    k_final   <<<dim3(2049, 8),     256, 0, stream>>>(out, wsf);
}

// Round 5
// 299.527 us; speedup vs baseline: 2.3066x; 2.3066x over previous
//
#include <hip/hip_runtime.h>
#include <math.h>

typedef unsigned short u16;
typedef __attribute__((ext_vector_type(8))) short bf16x8;
typedef __attribute__((ext_vector_type(4))) float f32x4;

#define BN 16
#define N 2048
#define D 256
#define PAIRS 8
#define NO 2049
#define NEGMIN  -3.40282347e38f
#define MASKVAL -3.0e38f          // stored sentinel: finite in bf16
#define LDA 72                    // padded LDS row stride (u16): 64 + 8

// ws float region (float offsets within wsf)
#define WS_LS0   0
#define WS_LS1   (1*PAIRS*N)
#define WS_LSN0  (2*PAIRS*N)
#define WS_LSN1  (3*PAIRS*N)
#define WS_RMAX  (4*PAIRS*N)
#define WS_RLSE  (5*PAIRS*N)
#define WS_CMAX  (6*PAIRS*N)
#define WS_CLSE  (7*PAIRS*N)
#define WS_CPM   (8*PAIRS*N)              // col partials max [PAIRS][16][N]
#define WS_CPS   (WS_CPM + PAIRS*16*N)    // col partials sum
#define WS_F_COUNT (WS_CPS + PAIRS*16*N)  // = 655360 floats (16B-aligned end)

__device__ __forceinline__ float b2f(u16 u) {
    return __uint_as_float(((unsigned)u) << 16);
}
__device__ __forceinline__ u16 f2b(float f) {  // RNE f32->bf16 (finite in)
    unsigned x = __float_as_uint(f);
    x += 0x7FFFu + ((x >> 16) & 1u);
    return (u16)(x >> 16);
}
__device__ __forceinline__ unsigned pk2(float a, float b) {
    return (unsigned)f2b(a) | ((unsigned)f2b(b) << 16);
}
__device__ __forceinline__ float logsig(float x) {
    return fminf(x, 0.f) - log1pf(expf(-fabsf(x)));
}
// online logsumexp accumulate, one exp per element
__device__ __forceinline__ void online1(float& m, float& s, float x) {
    float nm = fmaxf(m, x);
    float e = __expf(fminf(m, x) - nm);
    s = (x > m) ? s * e + 1.f : s + e;
    m = nm;
}
__device__ __forceinline__ void onmerge(float& m, float& s, float om, float os) {
    float nm = fmaxf(m, om);
    s = s * __expf(m - nm) + os * __expf(om - nm);
    m = nm;
}

// ---- matchability + logsig arrays (f32 inputs) ----
__global__ __launch_bounds__(256) void k_match(const float* __restrict__ desc,
                                               const float* __restrict__ mw,
                                               const float* __restrict__ mb,
                                               float* __restrict__ wsf) {
    int row = blockIdx.x * 4 + (threadIdx.x >> 6);
    int lane = threadIdx.x & 63;
    float4 d = *(const float4*)(desc + (size_t)row * D + lane * 4);
    float4 w = *(const float4*)(mw + lane * 4);
    float s = d.x * w.x + d.y * w.y + d.z * w.z + d.w * w.w;
    #pragma unroll
    for (int off = 32; off > 0; off >>= 1) s += __shfl_down(s, off, 64);
    if (lane == 0) {
        float m = s + mb[0];
        int b = row >> 11;
        int i = row & (N - 1);
        int p = b >> 1, sid = b & 1;
        float ls = logsig(m), lsn = logsig(-m);
        if (sid == 0) { wsf[WS_LS0 + p*N + i] = ls; wsf[WS_LSN0 + p*N + i] = lsn; }
        else          { wsf[WS_LS1 + p*N + i] = ls; wsf[WS_LSN1 + p*N + i] = lsn; }
    }
}

// ---- projection GEMM via MFMA, inline f32->bf16 conversion ----
// mdesc[r, j] = bf16( (sum_k desc[r,k]*W[j,k] + bias[j]) * 0.25 )
__global__ __launch_bounds__(256) void k_proj_mfma(const float* __restrict__ A,
                                                   const float* __restrict__ W,
                                                   const float* __restrict__ bias,
                                                   u16* __restrict__ mdesc) {
    __shared__ u16 As[128 * LDA];
    __shared__ u16 Bs[128 * LDA];
    int r0 = blockIdx.x * 128, c0 = blockIdx.y * 128;
    int tid = threadIdx.x;
    int w = tid >> 6, lane = tid & 63;
    int ln = lane & 15, q = lane >> 4;
    int wr0 = (w >> 1) * 64, wc0 = (w & 1) * 64;
    f32x4 zero = {0.f, 0.f, 0.f, 0.f};
    f32x4 acc[4][4];
    #pragma unroll
    for (int a = 0; a < 4; ++a)
        #pragma unroll
        for (int b = 0; b < 4; ++b) acc[a][b] = zero;

    for (int kb = 0; kb < D; kb += 64) {
        __syncthreads();
        #pragma unroll
        for (int t = 0; t < 4; ++t) {
            int c = t * 256 + tid;          // chunk 0..1023 (8 bf16 each)
            int row = c >> 3, part = c & 7;
            const float* ap = A + (size_t)(r0 + row) * D + kb + part * 8;
            float4 f0 = *(const float4*)ap;
            float4 f1 = *(const float4*)(ap + 4);
            uint4 va;
            va.x = pk2(f0.x, f0.y); va.y = pk2(f0.z, f0.w);
            va.z = pk2(f1.x, f1.y); va.w = pk2(f1.z, f1.w);
            *(uint4*)&As[row * LDA + part * 8] = va;
            const float* bp = W + (size_t)(c0 + row) * D + kb + part * 8;
            float4 g0 = *(const float4*)bp;
            float4 g1 = *(const float4*)(bp + 4);
            uint4 vb;
            vb.x = pk2(g0.x, g0.y); vb.y = pk2(g0.z, g0.w);
            vb.z = pk2(g1.x, g1.y); vb.w = pk2(g1.z, g1.w);
            *(uint4*)&Bs[row * LDA + part * 8] = vb;
        }
        __syncthreads();
        #pragma unroll
        for (int kk = 0; kk < 64; kk += 32) {
            bf16x8 af[4], bf[4];
            #pragma unroll
            for (int ri = 0; ri < 4; ++ri)
                af[ri] = *(const bf16x8*)&As[(wr0 + ri*16 + ln) * LDA + kk + q*8];
            #pragma unroll
            for (int ci = 0; ci < 4; ++ci)
                bf[ci] = *(const bf16x8*)&Bs[(wc0 + ci*16 + ln) * LDA + kk + q*8];
            #pragma unroll
            for (int ri = 0; ri < 4; ++ri)
                #pragma unroll
                for (int ci = 0; ci < 4; ++ci)
                    acc[ri][ci] = __builtin_amdgcn_mfma_f32_16x16x32_bf16(af[ri], bf[ci], acc[ri][ci], 0, 0, 0);
        }
    }
    #pragma unroll
    for (int ri = 0; ri < 4; ++ri) {
        #pragma unroll
        for (int reg = 0; reg < 4; ++reg) {
            int row = r0 + wr0 + ri*16 + q*4 + reg;
            #pragma unroll
            for (int ci = 0; ci < 4; ++ci) {
                int col = c0 + wc0 + ci*16 + ln;
                float v = (acc[ri][ci][reg] + bias[col]) * 0.25f;
                mdesc[(size_t)row * D + col] = f2b(v);
            }
        }
    }
}

// ---- similarity GEMM via MFMA: S = A0 @ A1^T, masked, bf16 into out inner NxN ----
__global__ __launch_bounds__(256) void k_sim_mfma(const u16* __restrict__ mdesc,
                                                  const int* __restrict__ mask,
                                                  u16* __restrict__ out) {
    __shared__ u16 As[128 * LDA];
    __shared__ u16 Bs[128 * LDA];
    int p = blockIdx.z;
    const u16* A  = mdesc + (size_t)(2*p) * N * D;
    const u16* Bm = mdesc + (size_t)(2*p + 1) * N * D;
    int r0 = blockIdx.x * 128, c0 = blockIdx.y * 128;
    int tid = threadIdx.x;
    int w = tid >> 6, lane = tid & 63;
    int ln = lane & 15, q = lane >> 4;
    int wr0 = (w >> 1) * 64, wc0 = (w & 1) * 64;
    f32x4 zero = {0.f, 0.f, 0.f, 0.f};
    f32x4 acc[4][4];
    #pragma unroll
    for (int a = 0; a < 4; ++a)
        #pragma unroll
        for (int b = 0; b < 4; ++b) acc[a][b] = zero;

    for (int kb = 0; kb < D; kb += 64) {
        __syncthreads();
        #pragma unroll
        for (int t = 0; t < 4; ++t) {
            int c = t * 256 + tid;
            int row = c >> 3, part = c & 7;
            uint4 va = *(const uint4*)(A  + (size_t)(r0 + row) * D + kb + part * 8);
            *(uint4*)&As[row * LDA + part * 8] = va;
            uint4 vb = *(const uint4*)(Bm + (size_t)(c0 + row) * D + kb + part * 8);
            *(uint4*)&Bs[row * LDA + part * 8] = vb;
        }
        __syncthreads();
        #pragma unroll
        for (int kk = 0; kk < 64; kk += 32) {
            bf16x8 af[4], bf[4];
            #pragma unroll
            for (int ri = 0; ri < 4; ++ri)
                af[ri] = *(const bf16x8*)&As[(wr0 + ri*16 + ln) * LDA + kk + q*8];
            #pragma unroll
            for (int ci = 0; ci < 4; ++ci)
                bf[ci] = *(const bf16x8*)&Bs[(wc0 + ci*16 + ln) * LDA + kk + q*8];
            #pragma unroll
            for (int ri = 0; ri < 4; ++ri)
                #pragma unroll
                for (int ci = 0; ci < 4; ++ci)
                    acc[ri][ci] = __builtin_amdgcn_mfma_f32_16x16x32_bf16(af[ri], bf[ci], acc[ri][ci], 0, 0, 0);
        }
    }
    const int* m0 = mask + (size_t)(2*p) * N;
    const int* m1 = mask + (size_t)(2*p + 1) * N;
    u16* outp = out + (size_t)p * NO * NO;
    int mcol[4];
    #pragma unroll
    for (int ci = 0; ci < 4; ++ci) mcol[ci] = m1[c0 + wc0 + ci*16 + ln];
    #pragma unroll
    for (int ri = 0; ri < 4; ++ri) {
        #pragma unroll
        for (int reg = 0; reg < 4; ++reg) {
            int row = r0 + wr0 + ri*16 + q*4 + reg;
            int mr = m0[row];
            size_t base = (size_t)row * NO + c0 + wc0 + ln;
            #pragma unroll
            for (int ci = 0; ci < 4; ++ci) {
                float v = (mr && mcol[ci]) ? acc[ri][ci][reg] : MASKVAL;
                outp[base + ci*16] = f2b(v);
            }
        }
    }
}

// ---- row stats: one wave per row, dword-packed loads, online lse ----
__global__ __launch_bounds__(256) void k_rowstats(const u16* __restrict__ out,
                                                  float* __restrict__ wsf) {
    int i = blockIdx.x * 4 + (threadIdx.x >> 6);
    int p = blockIdx.y;
    int lane = threadIdx.x & 63;
    size_t B0 = ((size_t)p * NO + i) * NO;     // u16 index of col 0
    const unsigned* up = (const unsigned*)out;
    int head = (int)(B0 & 1);
    size_t U0 = (B0 + head) >> 1;
    int nu = (2048 - head) >> 1;               // 1024 or 1023
    float m = NEGMIN, s = 0.f;
    for (int k = lane; k < nu; k += 64) {
        unsigned v = up[U0 + k];
        online1(m, s, b2f((u16)v));
        online1(m, s, b2f((u16)(v >> 16)));
    }
    if (head && lane == 0) {                   // col 0 and col 2047 leftovers
        online1(m, s, b2f(out[B0]));
        online1(m, s, b2f(out[B0 + 2047]));
    }
    #pragma unroll
    for (int off = 32; off > 0; off >>= 1) {
        float om = __shfl_down(m, off, 64);
        float os = __shfl_down(s, off, 64);
        onmerge(m, s, om, os);
    }
    if (lane == 0) {
        wsf[WS_RMAX + p * N + i] = m;
        wsf[WS_RLSE + p * N + i] = logf(s);
    }
}

// ---- col stats: partials over 128-row chunks (coalesced), then reduce ----
__global__ __launch_bounds__(256) void k_colstats(const u16* __restrict__ out,
                                                  float* __restrict__ wsf) {
    int cc = blockIdx.x;        // col chunk (8 x 256)
    int rc = blockIdx.y;        // row chunk (16 x 128)
    int p  = blockIdx.z;
    int c = cc * 256 + threadIdx.x;
    const u16* op = out + (size_t)p * NO * NO + c;
    size_t base = (size_t)rc * 128 * NO;
    float m = NEGMIN, s = 0.f;
    for (int r = 0; r < 128; ++r)
        online1(m, s, b2f(op[base + (size_t)r * NO]));
    wsf[WS_CPM + ((size_t)(p * 16 + rc)) * N + c] = m;
    wsf[WS_CPS + ((size_t)(p * 16 + rc)) * N + c] = s;
}

__global__ __launch_bounds__(256) void k_colred(float* __restrict__ wsf) {
    int cc = blockIdx.x, p = blockIdx.y;
    int c = cc * 256 + threadIdx.x;
    float m = NEGMIN, s = 0.f;
    for (int rc = 0; rc < 16; ++rc)
        onmerge(m, s, wsf[WS_CPM + ((size_t)(p*16 + rc)) * N + c],
                      wsf[WS_CPS + ((size_t)(p*16 + rc)) * N + c]);
    wsf[WS_CMAX + p * N + c] = m;
    wsf[WS_CLSE + p * N + c] = logf(s);
}

// ---- final: in-place transform + borders, dword-packed ----
__global__ __launch_bounds__(256) void k_final(u16* __restrict__ out,
                                               const float* __restrict__ wsf) {
    int i = blockIdx.x, p = blockIdx.y;
    int tid = threadIdx.x;
    size_t B0 = ((size_t)p * NO + i) * NO;
    unsigned* up = (unsigned*)out;
    int head = (int)(B0 & 1);
    size_t U0 = (B0 + head) >> 1;
    if (i < N) {
        float rm  = wsf[WS_RMAX + p*N + i];
        float rl  = wsf[WS_RLSE + p*N + i];
        float l0  = wsf[WS_LS0  + p*N + i];
        float ln0 = wsf[WS_LSN0 + p*N + i];
        // head=0: uints cover cols 0..2047; border col 2048 scalar.
        // head=1: col 0 scalar; uints cover cols 1..2048 (border packed in last).
        for (int k = tid; k < 1024; k += 256) {
            unsigned v = up[U0 + k];
            int j0 = 2*k + head;
            float o0, o1;
            {
                float x = b2f((u16)v);
                float a = (x - rm) - rl;
                float b = (x - wsf[WS_CMAX + p*N + j0]) - wsf[WS_CLSE + p*N + j0];
                o0 = fmaxf(fmaxf(a + b, MASKVAL) + (l0 + wsf[WS_LS1 + p*N + j0]), MASKVAL);
            }
            int j1 = j0 + 1;
            if (j1 < N) {
                float x = b2f((u16)(v >> 16));
                float a = (x - rm) - rl;
                float b = (x - wsf[WS_CMAX + p*N + j1]) - wsf[WS_CLSE + p*N + j1];
                o1 = fmaxf(fmaxf(a + b, MASKVAL) + (l0 + wsf[WS_LS1 + p*N + j1]), MASKVAL);
            } else {
                o1 = ln0;                     // border col (head=1 path)
            }
            up[U0 + k] = pk2(o0, o1);
        }
        if (tid == 0) {
            if (head) {                        // col 0 scalar
                float x = b2f(out[B0]);
                float a = (x - rm) - rl;
                float b = (x - wsf[WS_CMAX + p*N]) - wsf[WS_CLSE + p*N];
                out[B0] = f2b(fmaxf(fmaxf(a + b, MASKVAL) + (l0 + wsf[WS_LS1 + p*N]), MASKVAL));
            } else {                           // border col scalar
                out[B0 + N] = f2b(ln0);
            }
        }
    } else {
        // border row: cols 0..2047 = lsn1[j]; col 2048 = 0
        for (int k = tid; k < 1024; k += 256) {
            int j0 = 2*k + head;
            float o0 = (j0 < N) ? wsf[WS_LSN1 + p*N + j0] : 0.f;
            int j1 = j0 + 1;
            float o1 = (j1 < N) ? wsf[WS_LSN1 + p*N + j1] : 0.f;
            up[U0 + k] = pk2(o0, o1);
        }
        if (tid == 0) {
            if (head) out[B0] = f2b(wsf[WS_LSN1 + p*N]);
            else      out[B0 + N] = 0;
        }
    }
}

extern "C" void kernel_launch(void* const* d_in, const int* in_sizes, int n_in,
                              void* d_out, int out_size, void* d_ws, size_t ws_size,
                              hipStream_t stream) {
    const float* desc    = (const float*)d_in[0];
    const int*   mask    = (const int*)d_in[1];
    const float* proj_w  = (const float*)d_in[2];
    const float* proj_b  = (const float*)d_in[3];
    const float* match_w = (const float*)d_in[4];
    const float* match_b = (const float*)d_in[5];
    u16*   out = (u16*)d_out;
    float* wsf = (float*)d_ws;
    u16*   mdesc = (u16*)((char*)d_ws + (size_t)WS_F_COUNT * sizeof(float));

    k_match    <<<dim3(8192),        256, 0, stream>>>(desc, match_w, match_b, wsf);
    k_proj_mfma<<<dim3(256, 2),      256, 0, stream>>>(desc, proj_w, proj_b, mdesc);
    k_sim_mfma <<<dim3(16, 16, 8),   256, 0, stream>>>(mdesc, mask, out);
    k_rowstats <<<dim3(512, 8),      256, 0, stream>>>(out, wsf);
    k_colstats <<<dim3(8, 16, 8),    256, 0, stream>>>(out, wsf);
    k_colred   <<<dim3(8, 8),        256, 0, stream>>>(wsf);
    k_final    <<<dim3(2049, 8),     256, 0, stream>>>(out, wsf);
}

// Round 6
// 275.298 us; speedup vs baseline: 2.5096x; 1.0880x over previous
//
#include <hip/hip_runtime.h>
#include <math.h>

typedef unsigned short u16;
typedef __attribute__((ext_vector_type(8))) short bf16x8;
typedef __attribute__((ext_vector_type(4))) float f32x4;

#define BN 16
#define N 2048
#define D 256
#define PAIRS 8
#define NO 2049
#define NEGMIN  -3.40282347e38f
#define MASKVAL -3.0e38f          // stored sentinel: finite in bf16
#define LDA 72                    // padded LDS row stride (u16): 64 + 8

// ws float region (float offsets within wsf)
#define WS_LS0   0
#define WS_LS1   (1*PAIRS*N)
#define WS_LSN0  (2*PAIRS*N)
#define WS_LSN1  (3*PAIRS*N)
#define WS_RMAX  (4*PAIRS*N)
#define WS_RLSE  (5*PAIRS*N)
#define WS_CMAX  (6*PAIRS*N)
#define WS_CLSE  (7*PAIRS*N)
#define WS_RPM   (8*PAIRS*N)               // row partials max [PAIRS][16][N]
#define WS_RPS   (WS_RPM + PAIRS*16*N)
#define WS_CPM   (WS_RPS + PAIRS*16*N)     // col partials max [PAIRS][16][N]
#define WS_CPS   (WS_CPM + PAIRS*16*N)
#define WS_F_COUNT (WS_CPS + PAIRS*16*N)

__device__ __forceinline__ float b2f(u16 u) {
    return __uint_as_float(((unsigned)u) << 16);
}
__device__ __forceinline__ u16 f2b(float f) {  // RNE f32->bf16 (finite in)
    unsigned x = __float_as_uint(f);
    x += 0x7FFFu + ((x >> 16) & 1u);
    return (u16)(x >> 16);
}
__device__ __forceinline__ unsigned pk2(float a, float b) {
    return (unsigned)f2b(a) | ((unsigned)f2b(b) << 16);
}
__device__ __forceinline__ float logsig(float x) {
    return fminf(x, 0.f) - log1pf(expf(-fabsf(x)));
}
__device__ __forceinline__ void online1(float& m, float& s, float x) {
    float nm = fmaxf(m, x);
    float e = __expf(fminf(m, x) - nm);
    s = (x > m) ? s * e + 1.f : s + e;
    m = nm;
}
__device__ __forceinline__ void onmerge(float& m, float& s, float om, float os) {
    float nm = fmaxf(m, om);
    s = s * __expf(m - nm) + os * __expf(om - nm);
    m = nm;
}

// ---- projection GEMM via MFMA + fused matchability ----
// mdesc[r,j] = bf16((sum_k desc[r,k]*W[j,k] + bias[j]) * 0.25)
// blockIdx.y==0 blocks also compute m[r] = desc[r]·mw + mb and the logsig arrays.
__global__ __launch_bounds__(256) void k_proj_mfma(const float* __restrict__ A,
                                                   const float* __restrict__ W,
                                                   const float* __restrict__ bias,
                                                   const float* __restrict__ mw,
                                                   const float* __restrict__ mb,
                                                   u16* __restrict__ mdesc,
                                                   float* __restrict__ wsf) {
    __shared__ u16 As[128 * LDA];
    __shared__ u16 Bs[128 * LDA];
    int r0 = blockIdx.x * 128, c0 = blockIdx.y * 128;
    int tid = threadIdx.x;
    int w = tid >> 6, lane = tid & 63;
    int ln = lane & 15, q = lane >> 4;
    int wr0 = (w >> 1) * 64, wc0 = (w & 1) * 64;
    f32x4 zero = {0.f, 0.f, 0.f, 0.f};
    f32x4 acc[4][4];
    #pragma unroll
    for (int a = 0; a < 4; ++a)
        #pragma unroll
        for (int b = 0; b < 4; ++b) acc[a][b] = zero;
    float mdot[4] = {0.f, 0.f, 0.f, 0.f};
    int domatch = (blockIdx.y == 0);

    for (int kb = 0; kb < D; kb += 64) {
        __syncthreads();
        #pragma unroll
        for (int t = 0; t < 4; ++t) {
            int c = t * 256 + tid;          // chunk (8 bf16 each)
            int row = c >> 3, part = c & 7;
            const float* ap = A + (size_t)(r0 + row) * D + kb + part * 8;
            float4 f0 = *(const float4*)ap;
            float4 f1 = *(const float4*)(ap + 4);
            uint4 va;
            va.x = pk2(f0.x, f0.y); va.y = pk2(f0.z, f0.w);
            va.z = pk2(f1.x, f1.y); va.w = pk2(f1.z, f1.w);
            *(uint4*)&As[row * LDA + part * 8] = va;
            if (domatch) {
                float4 w0 = *(const float4*)(mw + kb + part * 8);
                float4 w1 = *(const float4*)(mw + kb + part * 8 + 4);
                mdot[t] += f0.x*w0.x + f0.y*w0.y + f0.z*w0.z + f0.w*w0.w
                         + f1.x*w1.x + f1.y*w1.y + f1.z*w1.z + f1.w*w1.w;
            }
            const float* bp = W + (size_t)(c0 + row) * D + kb + part * 8;
            float4 g0 = *(const float4*)bp;
            float4 g1 = *(const float4*)(bp + 4);
            uint4 vb;
            vb.x = pk2(g0.x, g0.y); vb.y = pk2(g0.z, g0.w);
            vb.z = pk2(g1.x, g1.y); vb.w = pk2(g1.z, g1.w);
            *(uint4*)&Bs[row * LDA + part * 8] = vb;
        }
        __syncthreads();
        #pragma unroll
        for (int kk = 0; kk < 64; kk += 32) {
            bf16x8 af[4], bf[4];
            #pragma unroll
            for (int ri = 0; ri < 4; ++ri)
                af[ri] = *(const bf16x8*)&As[(wr0 + ri*16 + ln) * LDA + kk + q*8];
            #pragma unroll
            for (int ci = 0; ci < 4; ++ci)
                bf[ci] = *(const bf16x8*)&Bs[(wc0 + ci*16 + ln) * LDA + kk + q*8];
            #pragma unroll
            for (int ri = 0; ri < 4; ++ri)
                #pragma unroll
                for (int ci = 0; ci < 4; ++ci)
                    acc[ri][ci] = __builtin_amdgcn_mfma_f32_16x16x32_bf16(af[ri], bf[ci], acc[ri][ci], 0, 0, 0);
        }
    }
    if (domatch) {
        #pragma unroll
        for (int t = 0; t < 4; ++t) {
            float s = mdot[t];
            s += __shfl_xor(s, 1, 64);
            s += __shfl_xor(s, 2, 64);
            s += __shfl_xor(s, 4, 64);
            if ((tid & 7) == 0) {
                int row_g = r0 + t * 32 + (tid >> 3);
                float m = s + mb[0];
                int b = row_g >> 11;
                int i = row_g & (N - 1);
                int pp = b >> 1, sid = b & 1;
                float ls = logsig(m), lsn = logsig(-m);
                if (sid == 0) { wsf[WS_LS0 + pp*N + i] = ls; wsf[WS_LSN0 + pp*N + i] = lsn; }
                else          { wsf[WS_LS1 + pp*N + i] = ls; wsf[WS_LSN1 + pp*N + i] = lsn; }
            }
        }
    }
    #pragma unroll
    for (int ri = 0; ri < 4; ++ri) {
        #pragma unroll
        for (int reg = 0; reg < 4; ++reg) {
            int row = r0 + wr0 + ri*16 + q*4 + reg;
            #pragma unroll
            for (int ci = 0; ci < 4; ++ci) {
                int col = c0 + wc0 + ci*16 + ln;
                float v = (acc[ri][ci][reg] + bias[col]) * 0.25f;
                mdesc[(size_t)row * D + col] = f2b(v);
            }
        }
    }
}

// ---- similarity GEMM via MFMA + fused masked write + row/col lse partials ----
__global__ __launch_bounds__(256) void k_sim_mfma(const u16* __restrict__ mdesc,
                                                  const int* __restrict__ mask,
                                                  u16* __restrict__ out,
                                                  float* __restrict__ wsf) {
    __shared__ u16 As[128 * LDA];
    __shared__ u16 Bs[128 * LDA];
    __shared__ float rpm[128][2], rps[128][2];
    __shared__ float cpm[128][2], cps[128][2];
    int p = blockIdx.z;
    const u16* A  = mdesc + (size_t)(2*p) * N * D;
    const u16* Bm = mdesc + (size_t)(2*p + 1) * N * D;
    int r0 = blockIdx.x * 128, c0 = blockIdx.y * 128;
    int tid = threadIdx.x;
    int w = tid >> 6, lane = tid & 63;
    int ln = lane & 15, q = lane >> 4;
    int wr0 = (w >> 1) * 64, wc0 = (w & 1) * 64;
    f32x4 zero = {0.f, 0.f, 0.f, 0.f};
    f32x4 acc[4][4];
    #pragma unroll
    for (int a = 0; a < 4; ++a)
        #pragma unroll
        for (int b = 0; b < 4; ++b) acc[a][b] = zero;

    for (int kb = 0; kb < D; kb += 64) {
        __syncthreads();
        #pragma unroll
        for (int t = 0; t < 4; ++t) {
            int c = t * 256 + tid;
            int row = c >> 3, part = c & 7;
            uint4 va = *(const uint4*)(A  + (size_t)(r0 + row) * D + kb + part * 8);
            *(uint4*)&As[row * LDA + part * 8] = va;
            uint4 vb = *(const uint4*)(Bm + (size_t)(c0 + row) * D + kb + part * 8);
            *(uint4*)&Bs[row * LDA + part * 8] = vb;
        }
        __syncthreads();
        #pragma unroll
        for (int kk = 0; kk < 64; kk += 32) {
            bf16x8 af[4], bf[4];
            #pragma unroll
            for (int ri = 0; ri < 4; ++ri)
                af[ri] = *(const bf16x8*)&As[(wr0 + ri*16 + ln) * LDA + kk + q*8];
            #pragma unroll
            for (int ci = 0; ci < 4; ++ci)
                bf[ci] = *(const bf16x8*)&Bs[(wc0 + ci*16 + ln) * LDA + kk + q*8];
            #pragma unroll
            for (int ri = 0; ri < 4; ++ri)
                #pragma unroll
                for (int ci = 0; ci < 4; ++ci)
                    acc[ri][ci] = __builtin_amdgcn_mfma_f32_16x16x32_bf16(af[ri], bf[ci], acc[ri][ci], 0, 0, 0);
        }
    }
    const int* m0 = mask + (size_t)(2*p) * N;
    const int* m1 = mask + (size_t)(2*p + 1) * N;
    u16* outp = out + (size_t)p * NO * NO;
    int mcol[4];
    #pragma unroll
    for (int ci = 0; ci < 4; ++ci) mcol[ci] = m1[c0 + wc0 + ci*16 + ln];
    // apply mask in place + store bf16
    #pragma unroll
    for (int ri = 0; ri < 4; ++ri) {
        #pragma unroll
        for (int reg = 0; reg < 4; ++reg) {
            int row = r0 + wr0 + ri*16 + q*4 + reg;
            int mr = m0[row];
            size_t base = (size_t)row * NO + c0 + wc0 + ln;
            #pragma unroll
            for (int ci = 0; ci < 4; ++ci) {
                float v = (mr && mcol[ci]) ? acc[ri][ci][reg] : MASKVAL;
                acc[ri][ci][reg] = v;
                outp[base + ci*16] = f2b(v);
            }
        }
    }
    // row partials: per (ri,reg) row, over this wave's 64 cols
    #pragma unroll
    for (int ri = 0; ri < 4; ++ri) {
        #pragma unroll
        for (int reg = 0; reg < 4; ++reg) {
            float m = acc[ri][0][reg], s = 1.f;
            online1(m, s, acc[ri][1][reg]);
            online1(m, s, acc[ri][2][reg]);
            online1(m, s, acc[ri][3][reg]);
            #pragma unroll
            for (int off = 1; off <= 8; off <<= 1) {
                float om = __shfl_xor(m, off, 64);
                float os = __shfl_xor(s, off, 64);
                onmerge(m, s, om, os);
            }
            if (ln == 0) {
                int rl = wr0 + ri*16 + q*4 + reg;
                rpm[rl][w & 1] = m; rps[rl][w & 1] = s;
            }
        }
    }
    // col partials: per ci column, over this wave's 64 rows
    #pragma unroll
    for (int ci = 0; ci < 4; ++ci) {
        float m = acc[0][ci][0], s = 1.f;
        #pragma unroll
        for (int ri = 0; ri < 4; ++ri)
            #pragma unroll
            for (int reg = 0; reg < 4; ++reg)
                if (!(ri == 0 && reg == 0)) online1(m, s, acc[ri][ci][reg]);
        #pragma unroll
        for (int off = 16; off <= 32; off <<= 1) {
            float om = __shfl_xor(m, off, 64);
            float os = __shfl_xor(s, off, 64);
            onmerge(m, s, om, os);
        }
        if (q == 0) {
            int cl = wc0 + ci*16 + ln;
            cpm[cl][w >> 1] = m; cps[cl][w >> 1] = s;
        }
    }
    __syncthreads();
    if (tid < 128) {
        float m = rpm[tid][0], s = rps[tid][0];
        onmerge(m, s, rpm[tid][1], rps[tid][1]);
        size_t o = (size_t)(p * 16 + blockIdx.y) * N + r0 + tid;
        wsf[WS_RPM + o] = m; wsf[WS_RPS + o] = s;
    } else {
        int c = tid - 128;
        float m = cpm[c][0], s = cps[c][0];
        onmerge(m, s, cpm[c][1], cps[c][1]);
        size_t o = (size_t)(p * 16 + blockIdx.x) * N + c0 + c;
        wsf[WS_CPM + o] = m; wsf[WS_CPS + o] = s;
    }
}

// ---- merge 16 chunk partials -> final row/col stats ----
__global__ __launch_bounds__(256) void k_red(float* __restrict__ wsf) {
    int i = blockIdx.x * 256 + threadIdx.x;
    int p = blockIdx.y;
    if (blockIdx.z == 0) {
        float m = wsf[WS_RPM + (size_t)(p*16) * N + i];
        float s = wsf[WS_RPS + (size_t)(p*16) * N + i];
        for (int cb = 1; cb < 16; ++cb)
            onmerge(m, s, wsf[WS_RPM + (size_t)(p*16 + cb) * N + i],
                          wsf[WS_RPS + (size_t)(p*16 + cb) * N + i]);
        wsf[WS_RMAX + p * N + i] = m;
        wsf[WS_RLSE + p * N + i] = logf(s);
    } else {
        float m = wsf[WS_CPM + (size_t)(p*16) * N + i];
        float s = wsf[WS_CPS + (size_t)(p*16) * N + i];
        for (int rb = 1; rb < 16; ++rb)
            onmerge(m, s, wsf[WS_CPM + (size_t)(p*16 + rb) * N + i],
                          wsf[WS_CPS + (size_t)(p*16 + rb) * N + i]);
        wsf[WS_CMAX + p * N + i] = m;
        wsf[WS_CLSE + p * N + i] = logf(s);
    }
}

// ---- final: in-place transform + borders, dword-packed ----
__global__ __launch_bounds__(256) void k_final(u16* __restrict__ out,
                                               const float* __restrict__ wsf) {
    int i = blockIdx.x, p = blockIdx.y;
    int tid = threadIdx.x;
    size_t B0 = ((size_t)p * NO + i) * NO;
    unsigned* up = (unsigned*)out;
    int head = (int)(B0 & 1);
    size_t U0 = (B0 + head) >> 1;
    if (i < N) {
        float rm  = wsf[WS_RMAX + p*N + i];
        float rl  = wsf[WS_RLSE + p*N + i];
        float l0  = wsf[WS_LS0  + p*N + i];
        float ln0 = wsf[WS_LSN0 + p*N + i];
        for (int k = tid; k < 1024; k += 256) {
            unsigned v = up[U0 + k];
            int j0 = 2*k + head;
            float o0, o1;
            {
                float x = b2f((u16)v);
                float a = (x - rm) - rl;
                float b = (x - wsf[WS_CMAX + p*N + j0]) - wsf[WS_CLSE + p*N + j0];
                o0 = fmaxf(fmaxf(a + b, MASKVAL) + (l0 + wsf[WS_LS1 + p*N + j0]), MASKVAL);
            }
            int j1 = j0 + 1;
            if (j1 < N) {
                float x = b2f((u16)(v >> 16));
                float a = (x - rm) - rl;
                float b = (x - wsf[WS_CMAX + p*N + j1]) - wsf[WS_CLSE + p*N + j1];
                o1 = fmaxf(fmaxf(a + b, MASKVAL) + (l0 + wsf[WS_LS1 + p*N + j1]), MASKVAL);
            } else {
                o1 = ln0;
            }
            up[U0 + k] = pk2(o0, o1);
        }
        if (tid == 0) {
            if (head) {
                float x = b2f(out[B0]);
                float a = (x - rm) - rl;
                float b = (x - wsf[WS_CMAX + p*N]) - wsf[WS_CLSE + p*N];
                out[B0] = f2b(fmaxf(fmaxf(a + b, MASKVAL) + (l0 + wsf[WS_LS1 + p*N]), MASKVAL));
            } else {
                out[B0 + N] = f2b(ln0);
            }
        }
    } else {
        for (int k = tid; k < 1024; k += 256) {
            int j0 = 2*k + head;
            float o0 = (j0 < N) ? wsf[WS_LSN1 + p*N + j0] : 0.f;
            int j1 = j0 + 1;
            float o1 = (j1 < N) ? wsf[WS_LSN1 + p*N + j1] : 0.f;
            up[U0 + k] = pk2(o0, o1);
        }
        if (tid == 0) {
            if (head) out[B0] = f2b(wsf[WS_LSN1 + p*N]);
            else      out[B0 + N] = 0;
        }
    }
}

extern "C" void kernel_launch(void* const* d_in, const int* in_sizes, int n_in,
                              void* d_out, int out_size, void* d_ws, size_t ws_size,
                              hipStream_t stream) {
    const float* desc    = (const float*)d_in[0];
    const int*   mask    = (const int*)d_in[1];
    const float* proj_w  = (const float*)d_in[2];
    const float* proj_b  = (const float*)d_in[3];
    const float* match_w = (const float*)d_in[4];
    const float* match_b = (const float*)d_in[5];
    u16*   out = (u16*)d_out;
    float* wsf = (float*)d_ws;
    u16*   mdesc = (u16*)((char*)d_ws + (size_t)WS_F_COUNT * sizeof(float));

    k_proj_mfma<<<dim3(256, 2),    256, 0, stream>>>(desc, proj_w, proj_b, match_w, match_b, mdesc, wsf);
    k_sim_mfma <<<dim3(16, 16, 8), 256, 0, stream>>>(mdesc, mask, out, wsf);
    k_red      <<<dim3(8, 8, 2),   256, 0, stream>>>(wsf);
    k_final    <<<dim3(2049, 8),   256, 0, stream>>>(out, wsf);
}